// Round 1
// baseline (24.901 us; speedup 1.0000x reference)
//
#include <hip/hip_runtime.h>

// Problem constants from setup_inputs(): bs=2, V=4096, N=32, S=8, K=64 (S*K=512)
#define BS 2
#define V_DIM 4096
#define N_NBR 32
#define S_SUP 8
#define K_OUT 64
#define SK (S_SUP * K_OUT)
#define WAVES_PER_BLOCK 4
#define EPS 1e-12f

__global__ __launch_bounds__(WAVES_PER_BLOCK * 64) void conv_surface_kernel(
    const int* __restrict__ nidx,     // (bs, V, N) int32
    const float* __restrict__ verts,  // (bs, V, 3) f32
    const float* __restrict__ dirs,   // (3, S*K)   f32
    float* __restrict__ out)          // (bs, V, K) f32
{
    const int lane = threadIdx.x & 63;
    const int wave = threadIdx.x >> 6;
    const int vi   = blockIdx.x * WAVES_PER_BLOCK + wave;   // in [0, BS*V)
    const int b    = vi / V_DIM;
    const int bbase = b * V_DIM;

    // normalized neighbor difference vectors, per wave
    __shared__ float snd[WAVES_PER_BLOCK][3][N_NBR];

    // center vertex (wave-uniform address -> cache broadcast)
    const float cx = verts[vi * 3 + 0];
    const float cy = verts[vi * 3 + 1];
    const float cz = verts[vi * 3 + 2];

    if (lane < N_NBR) {
        const int j = nidx[vi * N_NBR + lane];
        const float dx = verts[(bbase + j) * 3 + 0] - cx;
        const float dy = verts[(bbase + j) * 3 + 1] - cy;
        const float dz = verts[(bbase + j) * 3 + 2] - cz;
        const float inv = 1.0f / fmaxf(sqrtf(dx * dx + dy * dy + dz * dz), EPS);
        snd[wave][0][lane] = dx * inv;
        snd[wave][1][lane] = dy * inv;
        snd[wave][2][lane] = dz * inv;
    }
    __syncthreads();

    // Normalize this lane's 8 direction columns (m = s*64 + lane) into regs.
    float d0[S_SUP], d1[S_SUP], d2[S_SUP];
#pragma unroll
    for (int s = 0; s < S_SUP; ++s) {
        const int m = s * K_OUT + lane;
        const float a = dirs[0 * SK + m];
        const float bm = dirs[1 * SK + m];
        const float c = dirs[2 * SK + m];
        const float inv = 1.0f / fmaxf(sqrtf(a * a + bm * bm + c * c), EPS);
        d0[s] = a * inv;
        d1[s] = bm * inv;
        d2[s] = c * inv;
    }

    // relu + max over neighbors folds into max with 0 init.
    float th[S_SUP];
#pragma unroll
    for (int s = 0; s < S_SUP; ++s) th[s] = 0.0f;

#pragma unroll
    for (int n = 0; n < N_NBR; ++n) {
        const float nx = snd[wave][0][n];  // broadcast LDS reads, conflict-free
        const float ny = snd[wave][1][n];
        const float nz = snd[wave][2][n];
#pragma unroll
        for (int s = 0; s < S_SUP; ++s) {
            const float dot = nx * d0[s] + ny * d1[s] + nz * d2[s];
            th[s] = fmaxf(th[s], dot);
        }
    }

    float acc = 0.0f;
#pragma unroll
    for (int s = 0; s < S_SUP; ++s) acc += th[s];

    out[vi * K_OUT + lane] = acc;  // coalesced 256B per wave
}

extern "C" void kernel_launch(void* const* d_in, const int* in_sizes, int n_in,
                              void* d_out, int out_size, void* d_ws, size_t ws_size,
                              hipStream_t stream) {
    const int*   nidx  = (const int*)d_in[0];
    const float* verts = (const float*)d_in[1];
    const float* dirs  = (const float*)d_in[2];
    float*       out   = (float*)d_out;

    const int total_v = BS * V_DIM;                       // 8192
    const int blocks  = total_v / WAVES_PER_BLOCK;        // 2048
    conv_surface_kernel<<<blocks, WAVES_PER_BLOCK * 64, 0, stream>>>(nidx, verts, dirs, out);
}

// Round 2
// 18.213 us; speedup vs baseline: 1.3672x; 1.3672x over previous
//
#include <hip/hip_runtime.h>

// Problem constants from setup_inputs(): bs=2, V=4096, N=32, S=8, K=64 (S*K=512)
#define BS 2
#define V_DIM 4096
#define N_NBR 32
#define S_SUP 8
#define K_OUT 64
#define SK (S_SUP * K_OUT)
#define WAVES_PER_BLOCK 4
#define EPS 1e-12f

typedef float f32x2 __attribute__((ext_vector_type(2)));

__global__ __launch_bounds__(WAVES_PER_BLOCK * 64) void conv_surface_kernel(
    const int* __restrict__ nidx,     // (bs, V, N) int32
    const float* __restrict__ verts,  // (bs, V, 3) f32
    const float* __restrict__ dirs,   // (3, S*K)   f32
    float* __restrict__ out)          // (bs, V, K) f32
{
    const int lane = threadIdx.x & 63;
    const int wave = threadIdx.x >> 6;
    const int vi   = blockIdx.x * WAVES_PER_BLOCK + wave;   // in [0, BS*V)
    const int b    = vi / V_DIM;
    const int bbase = b * V_DIM;

    // normalized neighbor difference vectors, per wave
    __shared__ float snd[WAVES_PER_BLOCK][3][N_NBR];

    // ---- direction columns FIRST (independent of the gather chain) ----
    // lane owns columns m = s*64 + lane, s = 0..7, packed in pairs (2j, 2j+1).
    float a0[S_SUP], a1[S_SUP], a2[S_SUP];
#pragma unroll
    for (int s = 0; s < S_SUP; ++s) {
        const int m = s * K_OUT + lane;
        a0[s] = dirs[0 * SK + m];
        a1[s] = dirs[1 * SK + m];
        a2[s] = dirs[2 * SK + m];
    }

    // ---- gather + normalize neighbor diffs into LDS ----
    const float cx = verts[vi * 3 + 0];
    const float cy = verts[vi * 3 + 1];
    const float cz = verts[vi * 3 + 2];

    if (lane < N_NBR) {
        const int j = nidx[vi * N_NBR + lane];
        const float dx = verts[(bbase + j) * 3 + 0] - cx;
        const float dy = verts[(bbase + j) * 3 + 1] - cy;
        const float dz = verts[(bbase + j) * 3 + 2] - cz;
        const float inv = 1.0f / fmaxf(sqrtf(dx * dx + dy * dy + dz * dz), EPS);
        snd[wave][0][lane] = dx * inv;
        snd[wave][1][lane] = dy * inv;
        snd[wave][2][lane] = dz * inv;
    }

    // normalize this lane's direction columns, pack into f32x2 pairs
    f32x2 D0[S_SUP / 2], D1[S_SUP / 2], D2[S_SUP / 2];
#pragma unroll
    for (int j = 0; j < S_SUP / 2; ++j) {
        const int s0 = 2 * j, s1 = 2 * j + 1;
        const float i0 = 1.0f / fmaxf(sqrtf(a0[s0] * a0[s0] + a1[s0] * a1[s0] + a2[s0] * a2[s0]), EPS);
        const float i1 = 1.0f / fmaxf(sqrtf(a0[s1] * a0[s1] + a1[s1] * a1[s1] + a2[s1] * a2[s1]), EPS);
        D0[j] = (f32x2){a0[s0] * i0, a0[s1] * i1};
        D1[j] = (f32x2){a1[s0] * i0, a1[s1] * i1};
        D2[j] = (f32x2){a2[s0] * i0, a2[s1] * i1};
    }

    __syncthreads();

    // relu + max over neighbors folds into max with 0 init.
    f32x2 th[S_SUP / 2];
#pragma unroll
    for (int j = 0; j < S_SUP / 2; ++j) th[j] = (f32x2){0.0f, 0.0f};

#pragma unroll
    for (int n = 0; n < N_NBR; ++n) {
        const float nx = snd[wave][0][n];  // broadcast LDS reads, conflict-free
        const float ny = snd[wave][1][n];
        const float nz = snd[wave][2][n];
        const f32x2 vx = (f32x2){nx, nx};
        const f32x2 vy = (f32x2){ny, ny};
        const f32x2 vz = (f32x2){nz, nz};
#pragma unroll
        for (int j = 0; j < S_SUP / 2; ++j) {
            f32x2 t = vx * D0[j];
            t = t + vy * D1[j];               // contracts to v_pk_fma_f32
            t = t + vz * D2[j];
            th[j] = __builtin_elementwise_max(th[j], t);  // v_pk_max_f32
        }
    }

    float acc = 0.0f;
#pragma unroll
    for (int j = 0; j < S_SUP / 2; ++j) acc += th[j].x + th[j].y;

    out[vi * K_OUT + lane] = acc;  // coalesced 256B per wave
}

extern "C" void kernel_launch(void* const* d_in, const int* in_sizes, int n_in,
                              void* d_out, int out_size, void* d_ws, size_t ws_size,
                              hipStream_t stream) {
    const int*   nidx  = (const int*)d_in[0];
    const float* verts = (const float*)d_in[1];
    const float* dirs  = (const float*)d_in[2];
    float*       out   = (float*)d_out;

    const int total_v = BS * V_DIM;                       // 8192
    const int blocks  = total_v / WAVES_PER_BLOCK;        // 2048
    conv_surface_kernel<<<blocks, WAVES_PER_BLOCK * 64, 0, stream>>>(nidx, verts, dirs, out);
}